// Round 18
// baseline (145.823 us; speedup 1.0000x reference)
//
#include <hip/hip_runtime.h>
#include <hip/hip_bf16.h>

#define HID 128
#define BSH 6                 // 64 dst nodes per bucket
#define BSZ 64
#define NBMAX 1024
#define HB 64                 // histogram slice blocks
#define STAGE_BLKS 128

typedef unsigned int uint;
typedef unsigned short ushort;
typedef __attribute__((ext_vector_type(8))) short short8;
typedef __attribute__((ext_vector_type(4))) float f32x4;

__device__ __forceinline__ ushort bf16_of(float x) {
    return __bfloat16_as_ushort(__float2bfloat16(x));   // RNE
}

__device__ __forceinline__ uint pack_bf16x2(float a, float b) {
    return (uint)bf16_of(a) | ((uint)bf16_of(b) << 16);
}

union FragAB { uint4 u; short8 s; };

// ---------------- W pre-pack (both layers) + per-slice hist ----------------
__global__ __launch_bounds__(256) void pack_hist(
    const float* __restrict__ W1, const float* __restrict__ W2,
    ushort* __restrict__ Wb1, ushort* __restrict__ Wb2,
    const int* __restrict__ dst, int* __restrict__ hpart, int E, int NB) {
    int blk = blockIdx.x;
    if (blk >= 24) {
        __shared__ int h[NBMAX];
        int hb = blk - 24;
        for (int i = threadIdx.x; i < NB; i += 256) h[i] = 0;
        __syncthreads();
        int chunk = (E + HB - 1) / HB;
        int c0 = hb * chunk;
        int c1 = min(c0 + chunk, E);
        for (int e = c0 + threadIdx.x; e < c1; e += 256)
            atomicAdd(&h[dst[e] >> BSH], 1);
        __syncthreads();
        for (int i = threadIdx.x; i < NB; i += 256) hpart[hb * NBMAX + i] = h[i];
        return;
    }
    const float* W = (blk < 16) ? W1 : W2;
    ushort* Wb = (blk < 16) ? Wb1 : Wb2;
    int K = (blk < 16) ? 256 : 128;
    int t = ((blk < 16) ? blk : blk - 16) * 256 + threadIdx.x;
    int lane = t & 63, f = t >> 6;
    int s = f >> 3, c = f & 7;
    int m = c * 16 + (lane & 15);
    int k0 = s * 32 + (lane >> 4) * 8;
    const float* wr = W + (size_t)m * K + k0;
    float4 a = *(const float4*)wr;
    float4 b = *(const float4*)(wr + 4);
    uint4 o = make_uint4(pack_bf16x2(a.x, a.y), pack_bf16x2(a.z, a.w),
                         pack_bf16x2(b.x, b.y), pack_bf16x2(b.z, b.w));
    *(uint4*)(Wb + (size_t)t * 8) = o;
}

// ---------------- MFMA GEMM: LDS-staged B, double-buffered ----------------
template <int K, bool ABF16>
__device__ __forceinline__ void gemm_body(
    const void* __restrict__ Xv, const ushort* __restrict__ Wb,
    ushort* __restrict__ out, int N, int bid) {
    constexpr int NS = K / 32;
    __shared__ uint4 Bs[2][512];            // 2 x 8KB
    const int t    = threadIdx.x;
    const int lane = t & 63;
    const int wid  = t >> 6;
    const int n0   = bid * 64 + wid * 16;
    const int arow = min(n0 + (lane & 15), N - 1);   // clamp: OOB rows never stored
    const int kgrp = (lane >> 4) * 8;
    const float*  xrow_f = (const float*)Xv + (size_t)arow * K + kgrp;
    const ushort* xrow_h = (const ushort*)Xv + (size_t)arow * K + kgrp;
    const uint4* Wbv = (const uint4*)Wb;    // step s slot i: Wbv[s*512 + i]

    uint4 b0 = Wbv[t];
    uint4 b1 = Wbv[256 + t];
    float4 va, vb;
    uint4 ha;
    if (ABF16) ha = *(const uint4*)xrow_h;
    else { va = *(const float4*)xrow_f; vb = *(const float4*)(xrow_f + 4); }
    Bs[0][t] = b0;
    Bs[0][256 + t] = b1;
    __syncthreads();

    f32x4 acc[8];
#pragma unroll
    for (int c = 0; c < 8; ++c) acc[c] = (f32x4){0.f, 0.f, 0.f, 0.f};

#pragma unroll
    for (int s = 0; s < NS; ++s) {
        const int cur = s & 1;
        uint4 nb0, nb1;
        float4 nva, nvb;
        uint4 nha;
        if (s + 1 < NS) {
            nb0 = Wbv[(s + 1) * 512 + t];
            nb1 = Wbv[(s + 1) * 512 + 256 + t];
            if (ABF16) nha = *(const uint4*)(xrow_h + (s + 1) * 32);
            else {
                nva = *(const float4*)(xrow_f + (s + 1) * 32);
                nvb = *(const float4*)(xrow_f + (s + 1) * 32 + 4);
            }
        }
        FragAB af;
        if (ABF16) af.u = ha;
        else af.u = make_uint4(pack_bf16x2(va.x, va.y), pack_bf16x2(va.z, va.w),
                               pack_bf16x2(vb.x, vb.y), pack_bf16x2(vb.z, vb.w));
#pragma unroll
        for (int c = 0; c < 8; ++c) {
            FragAB bfr;
            bfr.u = Bs[cur][c * 64 + lane];
            acc[c] = __builtin_amdgcn_mfma_f32_16x16x32_bf16(af.s, bfr.s, acc[c], 0, 0, 0);
        }
        if (s + 1 < NS) {
            Bs[cur ^ 1][t] = nb0;
            Bs[cur ^ 1][256 + t] = nb1;
            ha = nha; va = nva; vb = nvb;
        }
        __syncthreads();
    }

    const int col = lane & 15;
    const int rb = n0 + (lane >> 4) * 4;
#pragma unroll
    for (int c = 0; c < 8; ++c) {
#pragma unroll
        for (int r = 0; r < 4; ++r) {
            int n = rb + r;
            if (n < N) out[(size_t)n * HID + c * 16 + col] = bf16_of(acc[c][r]);
        }
    }
}

// standalone gemms (DE-FUSED this round for per-dispatch attribution)
template <int K, bool ABF16>
__global__ __launch_bounds__(256) void gemm_mfma(
    const void* __restrict__ Xv, const ushort* __restrict__ Wb,
    ushort* __restrict__ out, int N) {
    gemm_body<K, ABF16>(Xv, Wb, out, N, blockIdx.x);
}

// ---------------- stage (standalone, global-atomic gcur reservation) ----------
__global__ __launch_bounds__(256) void bucket_stage(
    const int* __restrict__ src, const int* __restrict__ dst,
    const float* __restrict__ w, int* __restrict__ gcur,
    int2* __restrict__ staged, int E, int NB) {
    __shared__ int lh[NBMAX], lb[NBMAX];
    for (int i = threadIdx.x; i < NB; i += 256) lh[i] = 0;
    __syncthreads();
    int chunk = (E + STAGE_BLKS - 1) / STAGE_BLKS;
    int c0 = blockIdx.x * chunk;
    int c1 = min(c0 + chunk, E);
    for (int e = c0 + threadIdx.x; e < c1; e += 256)
        atomicAdd(&lh[dst[e] >> BSH], 1);
    __syncthreads();
    for (int i = threadIdx.x; i < NB; i += 256) {
        int c = lh[i];
        lb[i] = c ? atomicAdd(&gcur[i], c) : 0;
        lh[i] = 0;                           // reuse as local cursor
    }
    __syncthreads();
    for (int e = c0 + threadIdx.x; e < c1; e += 256) {
        int d = dst[e];
        int b = d >> BSH;
        int slot = lb[b] + atomicAdd(&lh[b], 1);
        staged[slot] = make_int2(src[e] | ((d & (BSZ - 1)) << 16), __float_as_int(w[e]));
    }
}

// ---------------- bucket scan ----------------
__global__ __launch_bounds__(NBMAX) void bucket_scan(const int* __restrict__ hpart,
                                                     int* __restrict__ gbase,
                                                     int* __restrict__ gcur, int NB, int E) {
    __shared__ int l[NBMAX];
    int t = threadIdx.x;
    int v = 0;
    if (t < NB)
        for (int b = 0; b < HB; ++b) v += hpart[b * NBMAX + t];
    l[t] = v;
    __syncthreads();
    int x = v;
    for (int o = 1; o < NBMAX; o <<= 1) {
        int y = (t >= o) ? l[t - o] : 0;
        __syncthreads();
        x += y;
        l[t] = x;
        __syncthreads();
    }
    if (t < NB) { gbase[t] = x - v; gcur[t] = x - v; }
    if (t == 0) gbase[NB] = E;
}

// one block per bucket: sort bucket's segment by local node into csr; emit off[].
__global__ __launch_bounds__(256) void node_sort(
    const int* __restrict__ gbase, const int2* __restrict__ staged,
    int2* __restrict__ csr, int* __restrict__ off, int N) {
    __shared__ int hist[BSZ];
    __shared__ int cur[BSZ];
    const int b = blockIdx.x;
    const int s0 = gbase[b], s1 = gbase[b + 1];
    const int t = threadIdx.x;
    if (t < BSZ) hist[t] = 0;
    __syncthreads();
    for (int e = s0 + t; e < s1; e += 256)
        atomicAdd(&hist[(staged[e].x >> 16) & (BSZ - 1)], 1);
    __syncthreads();
    if (t < BSZ) {                         // wave 0: shfl inclusive scan
        int x = hist[t];
        int incl = x;
#pragma unroll
        for (int o = 1; o < BSZ; o <<= 1) {
            int y = __shfl_up(incl, o, BSZ);
            if (t >= o) incl += y;
        }
        int excl = incl - x;
        cur[t] = excl;
        int n = (b << BSH) + t;
        if (n <= N) off[n] = s0 + excl;
    }
    __syncthreads();
    for (int e = s0 + t; e < s1; e += 256) {
        int2 m = staged[e];
        int d = (m.x >> 16) & (BSZ - 1);
        int p = atomicAdd(&cur[d], 1);
        csr[s0 + p] = m;
    }
}

// ---------------- pull-mode SpMM over bf16 features, lane-split rows ----------------
template <bool OUTBF16>
__global__ __launch_bounds__(256) void csr_gather_bf16(
    const int* __restrict__ off, const int2* __restrict__ edges,
    const ushort* __restrict__ fts, void* __restrict__ outv,
    const float* __restrict__ bias, const float* __restrict__ alpha, int N) {
    int d = blockIdx.x * 4 + (threadIdx.x >> 6);
    if (d >= N) return;
    const int lane = threadIdx.x & 63;
    const int g = lane >> 4;        // edge slot within 4-edge batch
    const int sub = lane & 15;      // col block: cols sub*8 .. sub*8+7
    int p = off[d];
    const int end = off[d + 1];
    float acc[8];
#pragma unroll
    for (int j = 0; j < 8; ++j) acc[j] = 0.f;

#define LOBITS(u_) __uint_as_float((u_) << 16)
#define HIBITS(u_) __uint_as_float((u_) & 0xffff0000u)
#define ROWOF(M_) (*(const uint4*)(fts + (size_t)((M_).x & 0xffff) * HID + sub * 8))
#define ACC8(R_, W_)                                              \
    do {                                                          \
        acc[0] += (W_) * LOBITS((R_).x); acc[1] += (W_) * HIBITS((R_).x); \
        acc[2] += (W_) * LOBITS((R_).y); acc[3] += (W_) * HIBITS((R_).y); \
        acc[4] += (W_) * LOBITS((R_).z); acc[5] += (W_) * HIBITS((R_).z); \
        acc[6] += (W_) * LOBITS((R_).w); acc[7] += (W_) * HIBITS((R_).w); \
    } while (0)

    for (; p + 16 <= end; p += 16) {               // 16 edges in flight (4KB)
        int2 m0 = edges[p + g], m1 = edges[p + 4 + g];
        int2 m2 = edges[p + 8 + g], m3 = edges[p + 12 + g];
        uint4 r0 = ROWOF(m0), r1 = ROWOF(m1), r2 = ROWOF(m2), r3 = ROWOF(m3);
        float w0 = __int_as_float(m0.y), w1 = __int_as_float(m1.y);
        float w2 = __int_as_float(m2.y), w3 = __int_as_float(m3.y);
        ACC8(r0, w0); ACC8(r1, w1); ACC8(r2, w2); ACC8(r3, w3);
    }
    for (; p + 8 <= end; p += 8) {
        int2 ma = edges[p + g];
        int2 mb = edges[p + 4 + g];
        uint4 ra = ROWOF(ma), rb = ROWOF(mb);
        float wa = __int_as_float(ma.y), wb = __int_as_float(mb.y);
        ACC8(ra, wa);
        ACC8(rb, wb);
    }
    for (; p < end; p += 4) {                      // masked 4-edge tail
        int i = p + g;
        int2 m = edges[(i < end) ? i : (end - 1)];
        float wt = (i < end) ? __int_as_float(m.y) : 0.f;
        uint4 r = ROWOF(m);
        ACC8(r, wt);
    }
#undef ACC8
#undef ROWOF
#undef LOBITS
#undef HIBITS

#pragma unroll
    for (int j = 0; j < 8; ++j) {                  // fold the 4 edge-groups
        acc[j] += __shfl_xor(acc[j], 16);
        acc[j] += __shfl_xor(acc[j], 32);
    }

    const float a = alpha[0];
#pragma unroll
    for (int j = 0; j < 8; ++j) {
        float v = acc[j] + bias[sub * 8 + j];
        acc[j] = v >= 0.f ? v : a * v;
    }
    if (g == 0) {
        if (OUTBF16) {
            uint4 o = make_uint4(pack_bf16x2(acc[0], acc[1]), pack_bf16x2(acc[2], acc[3]),
                                 pack_bf16x2(acc[4], acc[5]), pack_bf16x2(acc[6], acc[7]));
            *(uint4*)((ushort*)outv + (size_t)d * HID + sub * 8) = o;
        } else {
            float* op = (float*)outv + (size_t)d * HID + sub * 8;
            *(float4*)op = make_float4(acc[0], acc[1], acc[2], acc[3]);
            *(float4*)(op + 4) = make_float4(acc[4], acc[5], acc[6], acc[7]);
        }
    }
}

extern "C" void kernel_launch(void* const* d_in, const int* in_sizes, int n_in,
                              void* d_out, int out_size, void* d_ws, size_t ws_size,
                              hipStream_t stream) {
    const float* x  = (const float*)d_in[0];
    const int*   ei = (const int*)d_in[1];
    const float* ew = (const float*)d_in[2];
    const float* W1 = (const float*)d_in[3];
    const float* b1 = (const float*)d_in[4];
    const float* a1 = (const float*)d_in[5];
    const float* W2 = (const float*)d_in[6];
    const float* b2 = (const float*)d_in[7];
    const float* a2 = (const float*)d_in[8];
    float* out = (float*)d_out;

    int N = in_sizes[0] / 256;   // 50000 (fits in 16 bits for edge packing)
    int E = in_sizes[2];         // 800000
    const int* src = ei;
    const int* dst = ei + E;
    int NB = (N + BSZ - 1) >> BSH;   // 782

    // workspace layout
    ushort* fts    = (ushort*)d_ws;                   // N*HID bf16
    ushort* agg    = fts + (size_t)N * HID;           // N*HID bf16
    int2*   staged = (int2*)(agg + (size_t)N * HID);  // E
    int2*   csr    = staged + E;                      // E
    ushort* Wb1    = (ushort*)(csr + E);              // 128*256
    ushort* Wb2    = Wb1 + 128 * 256;                 // 128*128
    int*    hpart  = (int*)(Wb2 + 128 * 128);         // HB*NBMAX
    int*    gbase  = hpart + HB * NBMAX;              // NBMAX+1
    int*    gcur   = gbase + NBMAX + 1;               // NBMAX
    int*    off    = gcur + NBMAX;                    // N+1

    int gblk = (N + 63) / 64;        // 782
    int ggrid = (N + 3) / 4;

    // D1: W pre-pack + hist slices
    pack_hist<<<24 + HB, 256, 0, stream>>>(W1, W2, Wb1, Wb2, dst, hpart, E, NB);
    // D2: bucket scan
    bucket_scan<<<1, NBMAX, 0, stream>>>(hpart, gbase, gcur, NB, E);
    // D3: bucket_stage STANDALONE (attribution round: was fused with gemm1)
    bucket_stage<<<STAGE_BLKS, 256, 0, stream>>>(src, dst, ew, gcur, staged, E, NB);
    // D4: node-level counting sort -> csr + off
    node_sort<<<NB, 256, 0, stream>>>(gbase, staged, csr, off, N);
    // D5: gemm1 STANDALONE (LDS-staged B)
    gemm_mfma<256, false><<<gblk, 256, 0, stream>>>(x, Wb1, fts, N);
    // D6: gather1 (bias1+PReLU1 fused, bf16 out)
    csr_gather_bf16<true><<<ggrid, 256, 0, stream>>>(off, csr, fts, agg, b1, a1, N);
    // D7: gemm2 (A bf16, LDS-staged B)
    gemm_mfma<128, true><<<gblk, 256, 0, stream>>>(agg, Wb2, fts, N);
    // D8: gather2 (bias2+PReLU2 fused, fp32 out)
    csr_gather_bf16<false><<<ggrid, 256, 0, stream>>>(off, csr, fts, out, b2, a2, N);
}

// Round 19
// 140.028 us; speedup vs baseline: 1.0414x; 1.0414x over previous
//
#include <hip/hip_runtime.h>
#include <hip/hip_bf16.h>

#define HID 128
#define BSH 6                 // 64 dst nodes per bucket
#define BSZ 64
#define NBMAX 1024
#define HB 64                 // histogram slice blocks
#define STAGE_BLKS 128

typedef unsigned int uint;
typedef unsigned short ushort;
typedef __attribute__((ext_vector_type(8))) short short8;
typedef __attribute__((ext_vector_type(4))) float f32x4;

__device__ __forceinline__ ushort bf16_of(float x) {
    return __bfloat16_as_ushort(__float2bfloat16(x));   // RNE
}

__device__ __forceinline__ uint pack_bf16x2(float a, float b) {
    return (uint)bf16_of(a) | ((uint)bf16_of(b) << 16);
}

union FragAB { uint4 u; short8 s; };

// ---------------- W pre-pack (both layers) + per-slice hist ----------------
__global__ __launch_bounds__(256) void pack_hist(
    const float* __restrict__ W1, const float* __restrict__ W2,
    ushort* __restrict__ Wb1, ushort* __restrict__ Wb2,
    const int* __restrict__ dst, int* __restrict__ hpart, int E, int NB) {
    int blk = blockIdx.x;
    if (blk >= 24) {
        __shared__ int h[NBMAX];
        int hb = blk - 24;
        for (int i = threadIdx.x; i < NB; i += 256) h[i] = 0;
        __syncthreads();
        int chunk = (E + HB - 1) / HB;
        int c0 = hb * chunk;
        int c1 = min(c0 + chunk, E);
        for (int e = c0 + threadIdx.x; e < c1; e += 256)
            atomicAdd(&h[dst[e] >> BSH], 1);
        __syncthreads();
        for (int i = threadIdx.x; i < NB; i += 256) hpart[hb * NBMAX + i] = h[i];
        return;
    }
    const float* W = (blk < 16) ? W1 : W2;
    ushort* Wb = (blk < 16) ? Wb1 : Wb2;
    int K = (blk < 16) ? 256 : 128;
    int t = ((blk < 16) ? blk : blk - 16) * 256 + threadIdx.x;
    int lane = t & 63, f = t >> 6;
    int s = f >> 3, c = f & 7;
    int m = c * 16 + (lane & 15);
    int k0 = s * 32 + (lane >> 4) * 8;
    const float* wr = W + (size_t)m * K + k0;
    float4 a = *(const float4*)wr;
    float4 b = *(const float4*)(wr + 4);
    uint4 o = make_uint4(pack_bf16x2(a.x, a.y), pack_bf16x2(a.z, a.w),
                         pack_bf16x2(b.x, b.y), pack_bf16x2(b.z, b.w));
    *(uint4*)(Wb + (size_t)t * 8) = o;
}

// ---------------- MFMA GEMM: LDS-staged B, double-buffered ----------------
template <int K, bool ABF16>
__device__ __forceinline__ void gemm_body(
    const void* __restrict__ Xv, const ushort* __restrict__ Wb,
    ushort* __restrict__ out, int N, int bid) {
    constexpr int NS = K / 32;
    __shared__ uint4 Bs[2][512];            // 2 x 8KB
    const int t    = threadIdx.x;
    const int lane = t & 63;
    const int wid  = t >> 6;
    const int n0   = bid * 64 + wid * 16;
    const int arow = min(n0 + (lane & 15), N - 1);   // clamp: OOB rows never stored
    const int kgrp = (lane >> 4) * 8;
    const float*  xrow_f = (const float*)Xv + (size_t)arow * K + kgrp;
    const ushort* xrow_h = (const ushort*)Xv + (size_t)arow * K + kgrp;
    const uint4* Wbv = (const uint4*)Wb;    // step s slot i: Wbv[s*512 + i]

    uint4 b0 = Wbv[t];
    uint4 b1 = Wbv[256 + t];
    float4 va, vb;
    uint4 ha;
    if (ABF16) ha = *(const uint4*)xrow_h;
    else { va = *(const float4*)xrow_f; vb = *(const float4*)(xrow_f + 4); }
    Bs[0][t] = b0;
    Bs[0][256 + t] = b1;
    __syncthreads();

    f32x4 acc[8];
#pragma unroll
    for (int c = 0; c < 8; ++c) acc[c] = (f32x4){0.f, 0.f, 0.f, 0.f};

#pragma unroll
    for (int s = 0; s < NS; ++s) {
        const int cur = s & 1;
        uint4 nb0, nb1;
        float4 nva, nvb;
        uint4 nha;
        if (s + 1 < NS) {
            nb0 = Wbv[(s + 1) * 512 + t];
            nb1 = Wbv[(s + 1) * 512 + 256 + t];
            if (ABF16) nha = *(const uint4*)(xrow_h + (s + 1) * 32);
            else {
                nva = *(const float4*)(xrow_f + (s + 1) * 32);
                nvb = *(const float4*)(xrow_f + (s + 1) * 32 + 4);
            }
        }
        FragAB af;
        if (ABF16) af.u = ha;
        else af.u = make_uint4(pack_bf16x2(va.x, va.y), pack_bf16x2(va.z, va.w),
                               pack_bf16x2(vb.x, vb.y), pack_bf16x2(vb.z, vb.w));
#pragma unroll
        for (int c = 0; c < 8; ++c) {
            FragAB bfr;
            bfr.u = Bs[cur][c * 64 + lane];
            acc[c] = __builtin_amdgcn_mfma_f32_16x16x32_bf16(af.s, bfr.s, acc[c], 0, 0, 0);
        }
        if (s + 1 < NS) {
            Bs[cur ^ 1][t] = nb0;
            Bs[cur ^ 1][256 + t] = nb1;
            ha = nha; va = nva; vb = nvb;
        }
        __syncthreads();
    }

    const int col = lane & 15;
    const int rb = n0 + (lane >> 4) * 4;
#pragma unroll
    for (int c = 0; c < 8; ++c) {
#pragma unroll
        for (int r = 0; r < 4; ++r) {
            int n = rb + r;
            if (n < N) out[(size_t)n * HID + c * 16 + col] = bf16_of(acc[c][r]);
        }
    }
}

// ---------------- stage device body (global-atomic gcur reservation) ----------
__device__ __forceinline__ void stage_body(
    const int* __restrict__ src, const int* __restrict__ dst,
    const float* __restrict__ w, int* __restrict__ gcur,
    int2* __restrict__ staged, int E, int NB, int bid) {
    __shared__ int lh[NBMAX], lb[NBMAX];
    for (int i = threadIdx.x; i < NB; i += 256) lh[i] = 0;
    __syncthreads();
    int chunk = (E + STAGE_BLKS - 1) / STAGE_BLKS;
    int c0 = bid * chunk;
    int c1 = min(c0 + chunk, E);
    for (int e = c0 + threadIdx.x; e < c1; e += 256)
        atomicAdd(&lh[dst[e] >> BSH], 1);
    __syncthreads();
    for (int i = threadIdx.x; i < NB; i += 256) {
        int c = lh[i];
        lb[i] = c ? atomicAdd(&gcur[i], c) : 0;
        lh[i] = 0;                           // reuse as local cursor
    }
    __syncthreads();
    for (int e = c0 + threadIdx.x; e < c1; e += 256) {
        int d = dst[e];
        int b = d >> BSH;
        int slot = lb[b] + atomicAdd(&lh[b], 1);
        staged[slot] = make_int2(src[e] | ((d & (BSZ - 1)) << 16), __float_as_int(w[e]));
    }
}

// ---------------- fused: stage (blocks 0..STAGE_BLKS-1, runs FIRST) + gemm1 ----------
// Stage blocks scheduled first so the build critical path (stage -> node_sort)
// starts immediately; the gemm tail then owns the whole machine.
__global__ __launch_bounds__(256) void gemm1_stage(
    const float* __restrict__ X, const ushort* __restrict__ Wb1,
    ushort* __restrict__ fts, int N,
    const int* __restrict__ src, const int* __restrict__ dst,
    const float* __restrict__ w, int* __restrict__ gcur,
    int2* __restrict__ staged, int E, int NB) {
    int bid = blockIdx.x;
    if (bid < STAGE_BLKS) {
        stage_body(src, dst, w, gcur, staged, E, NB, bid);
    } else {
        gemm_body<256, false>(X, Wb1, fts, N, bid - STAGE_BLKS);
    }
}

// standalone gemm for layer 2
template <int K, bool ABF16>
__global__ __launch_bounds__(256) void gemm_mfma(
    const void* __restrict__ Xv, const ushort* __restrict__ Wb,
    ushort* __restrict__ out, int N) {
    gemm_body<K, ABF16>(Xv, Wb, out, N, blockIdx.x);
}

// ---------------- bucket scan ----------------
__global__ __launch_bounds__(NBMAX) void bucket_scan(const int* __restrict__ hpart,
                                                     int* __restrict__ gbase,
                                                     int* __restrict__ gcur, int NB, int E) {
    __shared__ int l[NBMAX];
    int t = threadIdx.x;
    int v = 0;
    if (t < NB)
        for (int b = 0; b < HB; ++b) v += hpart[b * NBMAX + t];
    l[t] = v;
    __syncthreads();
    int x = v;
    for (int o = 1; o < NBMAX; o <<= 1) {
        int y = (t >= o) ? l[t - o] : 0;
        __syncthreads();
        x += y;
        l[t] = x;
        __syncthreads();
    }
    if (t < NB) { gbase[t] = x - v; gcur[t] = x - v; }
    if (t == 0) gbase[NB] = E;
}

// one block per bucket: sort bucket's segment by local node into csr; emit off[].
__global__ __launch_bounds__(256) void node_sort(
    const int* __restrict__ gbase, const int2* __restrict__ staged,
    int2* __restrict__ csr, int* __restrict__ off, int N) {
    __shared__ int hist[BSZ];
    __shared__ int cur[BSZ];
    const int b = blockIdx.x;
    const int s0 = gbase[b], s1 = gbase[b + 1];
    const int t = threadIdx.x;
    if (t < BSZ) hist[t] = 0;
    __syncthreads();
    for (int e = s0 + t; e < s1; e += 256)
        atomicAdd(&hist[(staged[e].x >> 16) & (BSZ - 1)], 1);
    __syncthreads();
    if (t < BSZ) {                         // wave 0: shfl inclusive scan
        int x = hist[t];
        int incl = x;
#pragma unroll
        for (int o = 1; o < BSZ; o <<= 1) {
            int y = __shfl_up(incl, o, BSZ);
            if (t >= o) incl += y;
        }
        int excl = incl - x;
        cur[t] = excl;
        int n = (b << BSH) + t;
        if (n <= N) off[n] = s0 + excl;
    }
    __syncthreads();
    for (int e = s0 + t; e < s1; e += 256) {
        int2 m = staged[e];
        int d = (m.x >> 16) & (BSZ - 1);
        int p = atomicAdd(&cur[d], 1);
        csr[s0 + p] = m;
    }
}

// ---------------- pull-mode SpMM over bf16 features, lane-split rows ----------------
template <bool OUTBF16>
__global__ __launch_bounds__(256) void csr_gather_bf16(
    const int* __restrict__ off, const int2* __restrict__ edges,
    const ushort* __restrict__ fts, void* __restrict__ outv,
    const float* __restrict__ bias, const float* __restrict__ alpha, int N) {
    int d = blockIdx.x * 4 + (threadIdx.x >> 6);
    if (d >= N) return;
    const int lane = threadIdx.x & 63;
    const int g = lane >> 4;        // edge slot within 4-edge batch
    const int sub = lane & 15;      // col block: cols sub*8 .. sub*8+7
    int p = off[d];
    const int end = off[d + 1];
    float acc[8];
#pragma unroll
    for (int j = 0; j < 8; ++j) acc[j] = 0.f;

#define LOBITS(u_) __uint_as_float((u_) << 16)
#define HIBITS(u_) __uint_as_float((u_) & 0xffff0000u)
#define ROWOF(M_) (*(const uint4*)(fts + (size_t)((M_).x & 0xffff) * HID + sub * 8))
#define ACC8(R_, W_)                                              \
    do {                                                          \
        acc[0] += (W_) * LOBITS((R_).x); acc[1] += (W_) * HIBITS((R_).x); \
        acc[2] += (W_) * LOBITS((R_).y); acc[3] += (W_) * HIBITS((R_).y); \
        acc[4] += (W_) * LOBITS((R_).z); acc[5] += (W_) * HIBITS((R_).z); \
        acc[6] += (W_) * LOBITS((R_).w); acc[7] += (W_) * HIBITS((R_).w); \
    } while (0)

    for (; p + 16 <= end; p += 16) {               // 16 edges in flight (4KB)
        int2 m0 = edges[p + g], m1 = edges[p + 4 + g];
        int2 m2 = edges[p + 8 + g], m3 = edges[p + 12 + g];
        uint4 r0 = ROWOF(m0), r1 = ROWOF(m1), r2 = ROWOF(m2), r3 = ROWOF(m3);
        float w0 = __int_as_float(m0.y), w1 = __int_as_float(m1.y);
        float w2 = __int_as_float(m2.y), w3 = __int_as_float(m3.y);
        ACC8(r0, w0); ACC8(r1, w1); ACC8(r2, w2); ACC8(r3, w3);
    }
    for (; p + 8 <= end; p += 8) {
        int2 ma = edges[p + g];
        int2 mb = edges[p + 4 + g];
        uint4 ra = ROWOF(ma), rb = ROWOF(mb);
        float wa = __int_as_float(ma.y), wb = __int_as_float(mb.y);
        ACC8(ra, wa);
        ACC8(rb, wb);
    }
    for (; p < end; p += 4) {                      // masked 4-edge tail
        int i = p + g;
        int2 m = edges[(i < end) ? i : (end - 1)];
        float wt = (i < end) ? __int_as_float(m.y) : 0.f;
        uint4 r = ROWOF(m);
        ACC8(r, wt);
    }
#undef ACC8
#undef ROWOF
#undef LOBITS
#undef HIBITS

#pragma unroll
    for (int j = 0; j < 8; ++j) {                  // fold the 4 edge-groups
        acc[j] += __shfl_xor(acc[j], 16);
        acc[j] += __shfl_xor(acc[j], 32);
    }

    const float a = alpha[0];
#pragma unroll
    for (int j = 0; j < 8; ++j) {
        float v = acc[j] + bias[sub * 8 + j];
        acc[j] = v >= 0.f ? v : a * v;
    }
    if (g == 0) {
        if (OUTBF16) {
            uint4 o = make_uint4(pack_bf16x2(acc[0], acc[1]), pack_bf16x2(acc[2], acc[3]),
                                 pack_bf16x2(acc[4], acc[5]), pack_bf16x2(acc[6], acc[7]));
            *(uint4*)((ushort*)outv + (size_t)d * HID + sub * 8) = o;
        } else {
            float* op = (float*)outv + (size_t)d * HID + sub * 8;
            *(float4*)op = make_float4(acc[0], acc[1], acc[2], acc[3]);
            *(float4*)(op + 4) = make_float4(acc[4], acc[5], acc[6], acc[7]);
        }
    }
}

extern "C" void kernel_launch(void* const* d_in, const int* in_sizes, int n_in,
                              void* d_out, int out_size, void* d_ws, size_t ws_size,
                              hipStream_t stream) {
    const float* x  = (const float*)d_in[0];
    const int*   ei = (const int*)d_in[1];
    const float* ew = (const float*)d_in[2];
    const float* W1 = (const float*)d_in[3];
    const float* b1 = (const float*)d_in[4];
    const float* a1 = (const float*)d_in[5];
    const float* W2 = (const float*)d_in[6];
    const float* b2 = (const float*)d_in[7];
    const float* a2 = (const float*)d_in[8];
    float* out = (float*)d_out;

    int N = in_sizes[0] / 256;   // 50000 (fits in 16 bits for edge packing)
    int E = in_sizes[2];         // 800000
    const int* src = ei;
    const int* dst = ei + E;
    int NB = (N + BSZ - 1) >> BSH;   // 782

    // workspace layout
    ushort* fts    = (ushort*)d_ws;                   // N*HID bf16
    ushort* agg    = fts + (size_t)N * HID;           // N*HID bf16
    int2*   staged = (int2*)(agg + (size_t)N * HID);  // E
    int2*   csr    = staged + E;                      // E
    ushort* Wb1    = (ushort*)(csr + E);              // 128*256
    ushort* Wb2    = Wb1 + 128 * 256;                 // 128*128
    int*    hpart  = (int*)(Wb2 + 128 * 128);         // HB*NBMAX
    int*    gbase  = hpart + HB * NBMAX;              // NBMAX+1
    int*    gcur   = gbase + NBMAX + 1;               // NBMAX
    int*    off    = gcur + NBMAX;                    // N+1

    int gblk = (N + 63) / 64;        // 782
    int ggrid = (N + 3) / 4;

    // D1: W pre-pack + hist slices
    pack_hist<<<24 + HB, 256, 0, stream>>>(W1, W2, Wb1, Wb2, dst, hpart, E, NB);
    // D2: bucket scan
    bucket_scan<<<1, NBMAX, 0, stream>>>(hpart, gbase, gcur, NB, E);
    // D3: stage (first) + gemm1 fused — proven ~5.6us overlap win
    gemm1_stage<<<STAGE_BLKS + gblk, 256, 0, stream>>>(
        x, Wb1, fts, N, src, dst, ew, gcur, staged, E, NB);
    // D4: node-level counting sort -> csr + off
    node_sort<<<NB, 256, 0, stream>>>(gbase, staged, csr, off, N);
    // D5: gather1 (bias1+PReLU1 fused, bf16 out)
    csr_gather_bf16<true><<<ggrid, 256, 0, stream>>>(off, csr, fts, agg, b1, a1, N);
    // D6: gemm2 (A bf16, LDS-staged B)
    gemm_mfma<128, true><<<gblk, 256, 0, stream>>>(agg, Wb2, fts, N);
    // D7: gather2 (bias2+PReLU2 fused, fp32 out)
    csr_gather_bf16<false><<<ggrid, 256, 0, stream>>>(off, csr, fts, out, b2, a2, N);
}

// Round 20
// 138.669 us; speedup vs baseline: 1.0516x; 1.0098x over previous
//
#include <hip/hip_runtime.h>
#include <hip/hip_bf16.h>

#define HID 128
#define BSH 6                 // 64 dst nodes per bucket
#define BSZ 64
#define NBMAX 1024
#define HB 64                 // histogram slice blocks
#define STAGE_BLKS 128

typedef unsigned int uint;
typedef unsigned short ushort;
typedef __attribute__((ext_vector_type(8))) short short8;
typedef __attribute__((ext_vector_type(4))) float f32x4;

__device__ __forceinline__ ushort bf16_of(float x) {
    return __bfloat16_as_ushort(__float2bfloat16(x));   // RNE
}

__device__ __forceinline__ uint pack_bf16x2(float a, float b) {
    return (uint)bf16_of(a) | ((uint)bf16_of(b) << 16);
}

union FragAB { uint4 u; short8 s; };

// shared-memory union: gemm branch uses bs (16KB); stage branch uses st (8KB).
// Without the union the fused kernel allocated 24KB/block and lost 40% occupancy.
union SharedMem {
    uint4 bs[2][512];                              // 16KB
    struct { int lh[NBMAX]; int lb[NBMAX]; } st;   // 8KB
};

// ---------------- W pre-pack (both layers) + per-slice hist ----------------
__global__ __launch_bounds__(256) void pack_hist(
    const float* __restrict__ W1, const float* __restrict__ W2,
    ushort* __restrict__ Wb1, ushort* __restrict__ Wb2,
    const int* __restrict__ dst, int* __restrict__ hpart, int E, int NB) {
    int blk = blockIdx.x;
    if (blk >= 24) {
        __shared__ int h[NBMAX];
        int hb = blk - 24;
        for (int i = threadIdx.x; i < NB; i += 256) h[i] = 0;
        __syncthreads();
        int chunk = (E + HB - 1) / HB;
        int c0 = hb * chunk;
        int c1 = min(c0 + chunk, E);
        for (int e = c0 + threadIdx.x; e < c1; e += 256)
            atomicAdd(&h[dst[e] >> BSH], 1);
        __syncthreads();
        for (int i = threadIdx.x; i < NB; i += 256) hpart[hb * NBMAX + i] = h[i];
        return;
    }
    const float* W = (blk < 16) ? W1 : W2;
    ushort* Wb = (blk < 16) ? Wb1 : Wb2;
    int K = (blk < 16) ? 256 : 128;
    int t = ((blk < 16) ? blk : blk - 16) * 256 + threadIdx.x;
    int lane = t & 63, f = t >> 6;
    int s = f >> 3, c = f & 7;
    int m = c * 16 + (lane & 15);
    int k0 = s * 32 + (lane >> 4) * 8;
    const float* wr = W + (size_t)m * K + k0;
    float4 a = *(const float4*)wr;
    float4 b = *(const float4*)(wr + 4);
    uint4 o = make_uint4(pack_bf16x2(a.x, a.y), pack_bf16x2(a.z, a.w),
                         pack_bf16x2(b.x, b.y), pack_bf16x2(b.z, b.w));
    *(uint4*)(Wb + (size_t)t * 8) = o;
}

// ---------------- MFMA GEMM body: LDS-staged B, double-buffered ----------------
template <int K, bool ABF16>
__device__ __forceinline__ void gemm_body(
    SharedMem& shm, const void* __restrict__ Xv, const ushort* __restrict__ Wb,
    ushort* __restrict__ out, int N, int bid) {
    constexpr int NS = K / 32;
    const int t    = threadIdx.x;
    const int lane = t & 63;
    const int wid  = t >> 6;
    const int n0   = bid * 64 + wid * 16;
    const int arow = min(n0 + (lane & 15), N - 1);   // clamp: OOB rows never stored
    const int kgrp = (lane >> 4) * 8;
    const float*  xrow_f = (const float*)Xv + (size_t)arow * K + kgrp;
    const ushort* xrow_h = (const ushort*)Xv + (size_t)arow * K + kgrp;
    const uint4* Wbv = (const uint4*)Wb;    // step s slot i: Wbv[s*512 + i]

    uint4 b0 = Wbv[t];
    uint4 b1 = Wbv[256 + t];
    float4 va, vb;
    uint4 ha;
    if (ABF16) ha = *(const uint4*)xrow_h;
    else { va = *(const float4*)xrow_f; vb = *(const float4*)(xrow_f + 4); }
    shm.bs[0][t] = b0;
    shm.bs[0][256 + t] = b1;
    __syncthreads();

    f32x4 acc[8];
#pragma unroll
    for (int c = 0; c < 8; ++c) acc[c] = (f32x4){0.f, 0.f, 0.f, 0.f};

#pragma unroll
    for (int s = 0; s < NS; ++s) {
        const int cur = s & 1;
        uint4 nb0, nb1;
        float4 nva, nvb;
        uint4 nha;
        if (s + 1 < NS) {
            nb0 = Wbv[(s + 1) * 512 + t];
            nb1 = Wbv[(s + 1) * 512 + 256 + t];
            if (ABF16) nha = *(const uint4*)(xrow_h + (s + 1) * 32);
            else {
                nva = *(const float4*)(xrow_f + (s + 1) * 32);
                nvb = *(const float4*)(xrow_f + (s + 1) * 32 + 4);
            }
        }
        FragAB af;
        if (ABF16) af.u = ha;
        else af.u = make_uint4(pack_bf16x2(va.x, va.y), pack_bf16x2(va.z, va.w),
                               pack_bf16x2(vb.x, vb.y), pack_bf16x2(vb.z, vb.w));
#pragma unroll
        for (int c = 0; c < 8; ++c) {
            FragAB bfr;
            bfr.u = shm.bs[cur][c * 64 + lane];
            acc[c] = __builtin_amdgcn_mfma_f32_16x16x32_bf16(af.s, bfr.s, acc[c], 0, 0, 0);
        }
        if (s + 1 < NS) {
            shm.bs[cur ^ 1][t] = nb0;
            shm.bs[cur ^ 1][256 + t] = nb1;
            ha = nha; va = nva; vb = nvb;
        }
        __syncthreads();
    }

    const int col = lane & 15;
    const int rb = n0 + (lane >> 4) * 4;
#pragma unroll
    for (int c = 0; c < 8; ++c) {
#pragma unroll
        for (int r = 0; r < 4; ++r) {
            int n = rb + r;
            if (n < N) out[(size_t)n * HID + c * 16 + col] = bf16_of(acc[c][r]);
        }
    }
}

// ---------------- stage body (global-atomic gcur reservation) ----------
__device__ __forceinline__ void stage_body(
    SharedMem& shm, const int* __restrict__ src, const int* __restrict__ dst,
    const float* __restrict__ w, int* __restrict__ gcur,
    int2* __restrict__ staged, int E, int NB, int bid) {
    int* lh = shm.st.lh;
    int* lb = shm.st.lb;
    for (int i = threadIdx.x; i < NB; i += 256) lh[i] = 0;
    __syncthreads();
    int chunk = (E + STAGE_BLKS - 1) / STAGE_BLKS;
    int c0 = bid * chunk;
    int c1 = min(c0 + chunk, E);
    for (int e = c0 + threadIdx.x; e < c1; e += 256)
        atomicAdd(&lh[dst[e] >> BSH], 1);
    __syncthreads();
    for (int i = threadIdx.x; i < NB; i += 256) {
        int c = lh[i];
        lb[i] = c ? atomicAdd(&gcur[i], c) : 0;
        lh[i] = 0;                           // reuse as local cursor
    }
    __syncthreads();
    for (int e = c0 + threadIdx.x; e < c1; e += 256) {
        int d = dst[e];
        int b = d >> BSH;
        int slot = lb[b] + atomicAdd(&lh[b], 1);
        staged[slot] = make_int2(src[e] | ((d & (BSZ - 1)) << 16), __float_as_int(w[e]));
    }
}

// ---------------- fused: stage (blocks 0..STAGE_BLKS-1, first) + gemm1 ----------
__global__ __launch_bounds__(256) void gemm1_stage(
    const float* __restrict__ X, const ushort* __restrict__ Wb1,
    ushort* __restrict__ fts, int N,
    const int* __restrict__ src, const int* __restrict__ dst,
    const float* __restrict__ w, int* __restrict__ gcur,
    int2* __restrict__ staged, int E, int NB) {
    __shared__ SharedMem shm;       // 16KB (union — was 24KB as separate arrays)
    int bid = blockIdx.x;
    if (bid < STAGE_BLKS) {
        stage_body(shm, src, dst, w, gcur, staged, E, NB, bid);
    } else {
        gemm_body<256, false>(shm, X, Wb1, fts, N, bid - STAGE_BLKS);
    }
}

// standalone gemm for layer 2
template <int K, bool ABF16>
__global__ __launch_bounds__(256) void gemm_mfma(
    const void* __restrict__ Xv, const ushort* __restrict__ Wb,
    ushort* __restrict__ out, int N) {
    __shared__ SharedMem shm;
    gemm_body<K, ABF16>(shm, Xv, Wb, out, N, blockIdx.x);
}

// ---------------- bucket scan ----------------
__global__ __launch_bounds__(NBMAX) void bucket_scan(const int* __restrict__ hpart,
                                                     int* __restrict__ gbase,
                                                     int* __restrict__ gcur, int NB, int E) {
    __shared__ int l[NBMAX];
    int t = threadIdx.x;
    int v = 0;
    if (t < NB)
        for (int b = 0; b < HB; ++b) v += hpart[b * NBMAX + t];
    l[t] = v;
    __syncthreads();
    int x = v;
    for (int o = 1; o < NBMAX; o <<= 1) {
        int y = (t >= o) ? l[t - o] : 0;
        __syncthreads();
        x += y;
        l[t] = x;
        __syncthreads();
    }
    if (t < NB) { gbase[t] = x - v; gcur[t] = x - v; }
    if (t == 0) gbase[NB] = E;
}

// one block per bucket: sort bucket's segment by local node into csr; emit off[].
__global__ __launch_bounds__(256) void node_sort(
    const int* __restrict__ gbase, const int2* __restrict__ staged,
    int2* __restrict__ csr, int* __restrict__ off, int N) {
    __shared__ int hist[BSZ];
    __shared__ int cur[BSZ];
    const int b = blockIdx.x;
    const int s0 = gbase[b], s1 = gbase[b + 1];
    const int t = threadIdx.x;
    if (t < BSZ) hist[t] = 0;
    __syncthreads();
    for (int e = s0 + t; e < s1; e += 256)
        atomicAdd(&hist[(staged[e].x >> 16) & (BSZ - 1)], 1);
    __syncthreads();
    if (t < BSZ) {                         // wave 0: shfl inclusive scan
        int x = hist[t];
        int incl = x;
#pragma unroll
        for (int o = 1; o < BSZ; o <<= 1) {
            int y = __shfl_up(incl, o, BSZ);
            if (t >= o) incl += y;
        }
        int excl = incl - x;
        cur[t] = excl;
        int n = (b << BSH) + t;
        if (n <= N) off[n] = s0 + excl;
    }
    __syncthreads();
    for (int e = s0 + t; e < s1; e += 256) {
        int2 m = staged[e];
        int d = (m.x >> 16) & (BSZ - 1);
        int p = atomicAdd(&cur[d], 1);
        csr[s0 + p] = m;
    }
}

// ---------------- pull-mode SpMM over bf16 features, lane-split rows ----------------
template <bool OUTBF16>
__global__ __launch_bounds__(256) void csr_gather_bf16(
    const int* __restrict__ off, const int2* __restrict__ edges,
    const ushort* __restrict__ fts, void* __restrict__ outv,
    const float* __restrict__ bias, const float* __restrict__ alpha, int N) {
    int d = blockIdx.x * 4 + (threadIdx.x >> 6);
    if (d >= N) return;
    const int lane = threadIdx.x & 63;
    const int g = lane >> 4;        // edge slot within 4-edge batch
    const int sub = lane & 15;      // col block: cols sub*8 .. sub*8+7
    int p = off[d];
    const int end = off[d + 1];
    float acc[8];
#pragma unroll
    for (int j = 0; j < 8; ++j) acc[j] = 0.f;

#define LOBITS(u_) __uint_as_float((u_) << 16)
#define HIBITS(u_) __uint_as_float((u_) & 0xffff0000u)
#define ROWOF(M_) (*(const uint4*)(fts + (size_t)((M_).x & 0xffff) * HID + sub * 8))
#define ACC8(R_, W_)                                              \
    do {                                                          \
        acc[0] += (W_) * LOBITS((R_).x); acc[1] += (W_) * HIBITS((R_).x); \
        acc[2] += (W_) * LOBITS((R_).y); acc[3] += (W_) * HIBITS((R_).y); \
        acc[4] += (W_) * LOBITS((R_).z); acc[5] += (W_) * HIBITS((R_).z); \
        acc[6] += (W_) * LOBITS((R_).w); acc[7] += (W_) * HIBITS((R_).w); \
    } while (0)

    for (; p + 16 <= end; p += 16) {               // 16 edges in flight (4KB)
        int2 m0 = edges[p + g], m1 = edges[p + 4 + g];
        int2 m2 = edges[p + 8 + g], m3 = edges[p + 12 + g];
        uint4 r0 = ROWOF(m0), r1 = ROWOF(m1), r2 = ROWOF(m2), r3 = ROWOF(m3);
        float w0 = __int_as_float(m0.y), w1 = __int_as_float(m1.y);
        float w2 = __int_as_float(m2.y), w3 = __int_as_float(m3.y);
        ACC8(r0, w0); ACC8(r1, w1); ACC8(r2, w2); ACC8(r3, w3);
    }
    for (; p + 8 <= end; p += 8) {
        int2 ma = edges[p + g];
        int2 mb = edges[p + 4 + g];
        uint4 ra = ROWOF(ma), rb = ROWOF(mb);
        float wa = __int_as_float(ma.y), wb = __int_as_float(mb.y);
        ACC8(ra, wa);
        ACC8(rb, wb);
    }
    for (; p < end; p += 4) {                      // masked 4-edge tail
        int i = p + g;
        int2 m = edges[(i < end) ? i : (end - 1)];
        float wt = (i < end) ? __int_as_float(m.y) : 0.f;
        uint4 r = ROWOF(m);
        ACC8(r, wt);
    }
#undef ACC8
#undef ROWOF
#undef LOBITS
#undef HIBITS

#pragma unroll
    for (int j = 0; j < 8; ++j) {                  // fold the 4 edge-groups
        acc[j] += __shfl_xor(acc[j], 16);
        acc[j] += __shfl_xor(acc[j], 32);
    }

    const float a = alpha[0];
#pragma unroll
    for (int j = 0; j < 8; ++j) {
        float v = acc[j] + bias[sub * 8 + j];
        acc[j] = v >= 0.f ? v : a * v;
    }
    if (g == 0) {
        if (OUTBF16) {
            uint4 o = make_uint4(pack_bf16x2(acc[0], acc[1]), pack_bf16x2(acc[2], acc[3]),
                                 pack_bf16x2(acc[4], acc[5]), pack_bf16x2(acc[6], acc[7]));
            *(uint4*)((ushort*)outv + (size_t)d * HID + sub * 8) = o;
        } else {
            float* op = (float*)outv + (size_t)d * HID + sub * 8;
            *(float4*)op = make_float4(acc[0], acc[1], acc[2], acc[3]);
            *(float4*)(op + 4) = make_float4(acc[4], acc[5], acc[6], acc[7]);
        }
    }
}

extern "C" void kernel_launch(void* const* d_in, const int* in_sizes, int n_in,
                              void* d_out, int out_size, void* d_ws, size_t ws_size,
                              hipStream_t stream) {
    const float* x  = (const float*)d_in[0];
    const int*   ei = (const int*)d_in[1];
    const float* ew = (const float*)d_in[2];
    const float* W1 = (const float*)d_in[3];
    const float* b1 = (const float*)d_in[4];
    const float* a1 = (const float*)d_in[5];
    const float* W2 = (const float*)d_in[6];
    const float* b2 = (const float*)d_in[7];
    const float* a2 = (const float*)d_in[8];
    float* out = (float*)d_out;

    int N = in_sizes[0] / 256;   // 50000 (fits in 16 bits for edge packing)
    int E = in_sizes[2];         // 800000
    const int* src = ei;
    const int* dst = ei + E;
    int NB = (N + BSZ - 1) >> BSH;   // 782

    // workspace layout
    ushort* fts    = (ushort*)d_ws;                   // N*HID bf16
    ushort* agg    = fts + (size_t)N * HID;           // N*HID bf16
    int2*   staged = (int2*)(agg + (size_t)N * HID);  // E
    int2*   csr    = staged + E;                      // E
    ushort* Wb1    = (ushort*)(csr + E);              // 128*256
    ushort* Wb2    = Wb1 + 128 * 256;                 // 128*128
    int*    hpart  = (int*)(Wb2 + 128 * 128);         // HB*NBMAX
    int*    gbase  = hpart + HB * NBMAX;              // NBMAX+1
    int*    gcur   = gbase + NBMAX + 1;               // NBMAX
    int*    off    = gcur + NBMAX;                    // N+1

    int gblk = (N + 63) / 64;        // 782
    int ggrid = (N + 3) / 4;

    // D1: W pre-pack + hist slices
    pack_hist<<<24 + HB, 256, 0, stream>>>(W1, W2, Wb1, Wb2, dst, hpart, E, NB);
    // D2: bucket scan
    bucket_scan<<<1, NBMAX, 0, stream>>>(hpart, gbase, gcur, NB, E);
    // D3: stage (first) + gemm1 fused, LDS union (16KB not 24KB)
    gemm1_stage<<<STAGE_BLKS + gblk, 256, 0, stream>>>(
        x, Wb1, fts, N, src, dst, ew, gcur, staged, E, NB);
    // D4: node-level counting sort -> csr + off
    node_sort<<<NB, 256, 0, stream>>>(gbase, staged, csr, off, N);
    // D5: gather1 (bias1+PReLU1 fused, bf16 out)
    csr_gather_bf16<true><<<ggrid, 256, 0, stream>>>(off, csr, fts, agg, b1, a1, N);
    // D6: gemm2 (A bf16, LDS-staged B)
    gemm_mfma<128, true><<<gblk, 256, 0, stream>>>(agg, Wb2, fts, N);
    // D7: gather2 (bias2+PReLU2 fused, fp32 out)
    csr_gather_bf16<false><<<ggrid, 256, 0, stream>>>(off, csr, fts, out, b2, a2, N);
}